// Round 4
// baseline (42.070 us; speedup 1.0000x reference)
//
#include <hip/hip_runtime.h>
#include <hip/hip_bf16.h>

// out[q] = min(|{r : dist(q,r) <= thr}|, 100) / 100   (top-k is unnecessary:
// any distance <= thr is among the 100 smallest unless count > 100, which clamps)
//
// Q=4096, R=16384, D=128. hit  <=>  dot(q,r) >= 0.5*|q|^2 + 0.5*(|r|^2 - thr^2)
// dot via bf16 MFMA; margin vs bf16 rounding is ~100 (sq_dist ~ 120..400 vs 0.25).

#define DIM   128
#define ROWB  256              // bytes per bf16 row
#define BM    128
#define BN    64
#define NSPLIT 32              // 32 segments x 512 refs

typedef __attribute__((ext_vector_type(8))) short short8;
typedef __attribute__((ext_vector_type(4))) float f32x4;

#define VMCNT0() asm volatile("s_waitcnt vmcnt(0)" ::: "memory")

// ---------------- prep: fp32 -> bf16, row norms, zero counts ----------------
__global__ void prep_kernel(const float* __restrict__ qe, const float* __restrict__ re,
                            __hip_bfloat16* __restrict__ qb, __hip_bfloat16* __restrict__ rb,
                            float* __restrict__ qsq, float* __restrict__ rsq,
                            float* __restrict__ counts, int Q, int R) {
    const int wave = threadIdx.x >> 6;
    const int lane = threadIdx.x & 63;
    const int row = blockIdx.x * 4 + wave;
    if (row >= Q + R) return;
    const float* src;
    __hip_bfloat16* dst;
    float* nrm;
    if (row < Q) {
        src = qe + (size_t)row * DIM;
        dst = qb + (size_t)row * DIM;
        nrm = qsq + row;
        if (lane == 0) counts[row] = 0.0f;
    } else {
        int r = row - Q;
        src = re + (size_t)r * DIM;
        dst = rb + (size_t)r * DIM;
        nrm = rsq + r;
    }
    float2 v = ((const float2*)src)[lane];
    float s = v.x * v.x + v.y * v.y;
    __hip_bfloat162 b;
    b.x = __float2bfloat16(v.x);
    b.y = __float2bfloat16(v.y);
    ((__hip_bfloat162*)dst)[lane] = b;
    #pragma unroll
    for (int off = 32; off > 0; off >>= 1) s += __shfl_down(s, off);
    if (lane == 0) *nrm = s;
}

// ---------------- main: A-in-regs, B depth-2 LDS ring, 4 blocks/CU ----------
__launch_bounds__(256, 4)
__global__ void dist_count_kernel(const __hip_bfloat16* __restrict__ qb,
                                  const __hip_bfloat16* __restrict__ rb,
                                  const float* __restrict__ qsq,
                                  const float* __restrict__ rsq,
                                  const float* __restrict__ thr_p,
                                  float* __restrict__ counts,
                                  int Q, int R) {
    __shared__ short Bs[2][BN * DIM];      // 2 x 16KB = 32KB -> 4 blocks/CU

    const int tid  = threadIdx.x;
    const int lane = tid & 63;
    const int wave = tid >> 6;

    const int seg  = R / NSPLIT;           // 512
    const int base = blockIdx.x * seg;
    const int tileM = blockIdx.y;
    const int NT = seg / BN;               // 8

    const int wrow = (wave >> 1) * 64;     // query sub-rows
    const int wcol = (wave & 1) * 32;      // ref sub-cols within tile
    const int lr = lane & 15;
    const int lk = lane >> 4;

    const char* qbc = (const char*)qb;
    const char* rbc = (const char*)rb;

    // per-lane staging offsets (precomputed once): linear LDS dest (required
    // by global_load_lds), XOR-swizzle folded into the GLOBAL source column.
    int srcoff[4], ldsoff[4];
    #pragma unroll
    for (int j = 0; j < 4; ++j) {
        const int lds_byte = (wave * 4 + j) * 1024 + lane * 16;
        const int row = lds_byte >> 8;     // 0..63
        const int col = lds_byte & 255;
        srcoff[j] = row * ROWB + (col ^ ((row & 7) << 4));
        ldsoff[j] = lds_byte;
    }
    auto stage = [&](const char* tilesrc, int bufsel) {
        #pragma unroll
        for (int j = 0; j < 4; ++j)
            __builtin_amdgcn_global_load_lds(
                (const __attribute__((address_space(1))) unsigned int*)(tilesrc + srcoff[j]),
                (__attribute__((address_space(3))) unsigned int*)((char*)&Bs[bufsel][0] + ldsoff[j]),
                16, 0, 0);
    };

    // ---- A fragments, full K=128, in registers (once per block) ----
    short8 a[4][4];                        // [ks][mi]
    #pragma unroll
    for (int ks = 0; ks < 4; ++ks)
        #pragma unroll
        for (int mi = 0; mi < 4; ++mi) {
            const int qrow = tileM * BM + wrow + mi * 16 + lr;
            a[ks][mi] = *(const short8*)(qbc + (size_t)qrow * ROWB + ks * 64 + lk * 16);
        }

    const float thr = *thr_p;
    const float bias = (thr >= 0.0f) ? -0.5f * thr * thr : 1e30f;  // rh = 0.5*rsq + bias

    // per-lane min over its 16 query-half-norms (for the screen)
    const float* qsqrow = qsq + tileM * BM + wrow;
    float minqh;
    {
        float mq = 1e30f;
        #pragma unroll
        for (int mi = 0; mi < 4; ++mi)
            #pragma unroll
            for (int reg = 0; reg < 4; ++reg)
                mq = fminf(mq, qsqrow[mi * 16 + lk * 4 + reg]);
        minqh = 0.5f * mq;
    }

    const float* rs = rsq + base + wcol + lr;          // advances by BN per tile
    const char* srcbase = rbc + (size_t)base * ROWB;   // advances by BN*ROWB

    stage(srcbase, 0);

    for (int t = 0; t < NT; ++t) {
        VMCNT0();                              // my 4 loads for tile t done
        __builtin_amdgcn_s_barrier();          // all waves' loads done
        __builtin_amdgcn_sched_barrier(0);
        if (t + 1 < NT)                        // buf (t+1)&1 last read before prev barrier
            stage(srcbase + (size_t)(t + 1) * BN * ROWB, (t + 1) & 1);

        const char* cur = (const char*)Bs[t & 1];
        f32x4 acc[4][2] = {};
        __builtin_amdgcn_s_setprio(1);
        #pragma unroll
        for (int ks = 0; ks < 4; ++ks) {
            short8 b[2];
            #pragma unroll
            for (int ni = 0; ni < 2; ++ni) {
                const int brow = wcol + ni * 16 + lr;
                const int cb = (ks * 64 + lk * 16) ^ ((brow & 7) << 4);
                b[ni] = *(const short8*)(cur + brow * ROWB + cb);
            }
            #pragma unroll
            for (int mi = 0; mi < 4; ++mi)
                #pragma unroll
                for (int ni = 0; ni < 2; ++ni)
                    acc[mi][ni] = __builtin_amdgcn_mfma_f32_16x16x32_bf16(a[ks][mi], b[ni], acc[mi][ni], 0, 0, 0);
        }
        __builtin_amdgcn_s_setprio(0);

        // ---- screened epilogue ----
        const float rh0 = fmaf(0.5f, rs[0],  bias);
        const float rh1 = fmaf(0.5f, rs[16], bias);
        const float minrh = fminf(rh0, rh1);

        f32x4 m4 = acc[0][0];
        #pragma unroll
        for (int mi = 0; mi < 4; ++mi)
            #pragma unroll
            for (int ni = 0; ni < 2; ++ni)
                if (mi || ni) {
                    #pragma unroll
                    for (int reg = 0; reg < 4; ++reg)
                        m4[reg] = fmaxf(m4[reg], acc[mi][ni][reg]);
                }
        const float mx = fmaxf(fmaxf(m4[0], m4[1]), fmaxf(m4[2], m4[3]));

        if (__any(mx >= minqh + minrh)) {      // rare slow path (generic-correct)
            #pragma unroll
            for (int mi = 0; mi < 4; ++mi)
                #pragma unroll
                for (int reg = 0; reg < 4; ++reg) {
                    const float qh = 0.5f * qsqrow[mi * 16 + lk * 4 + reg];
                    float cnt = 0.0f;
                    if (acc[mi][0][reg] >= qh + rh0) cnt += 1.0f;
                    if (acc[mi][1][reg] >= qh + rh1) cnt += 1.0f;
                    cnt += __shfl_xor(cnt, 1);
                    cnt += __shfl_xor(cnt, 2);
                    cnt += __shfl_xor(cnt, 4);
                    cnt += __shfl_xor(cnt, 8);
                    if (lr == 0 && cnt != 0.0f) {
                        const int row = tileM * BM + wrow + mi * 16 + lk * 4 + reg;
                        atomicAdd(&counts[row], cnt);
                    }
                }
        }
        rs += BN;
    }
}

// ---------------- finalize ----------------
__global__ void finalize_kernel(const float* __restrict__ counts,
                                float* __restrict__ out, int Q, int R) {
    int q = blockIdx.x * blockDim.x + threadIdx.x;
    if (q < Q) {
        float k = (R < 100) ? (float)R : 100.0f;
        out[q] = fminf(counts[q], k) / k;
    }
}

extern "C" void kernel_launch(void* const* d_in, const int* in_sizes, int n_in,
                              void* d_out, int out_size, void* d_ws, size_t ws_size,
                              hipStream_t stream) {
    const float* qe  = (const float*)d_in[0];
    const float* re  = (const float*)d_in[1];
    const float* thr = (const float*)d_in[2];
    float* out = (float*)d_out;

    const int Q = in_sizes[0] / DIM;   // 4096
    const int R = in_sizes[1] / DIM;   // 16384

    char* ws = (char*)d_ws;
    __hip_bfloat16* qb = (__hip_bfloat16*)ws;
    __hip_bfloat16* rb = (__hip_bfloat16*)(ws + (size_t)Q * DIM * 2);
    float* qsq    = (float*)(ws + (size_t)(Q + R) * DIM * 2);
    float* rsq    = qsq + Q;
    float* counts = rsq + R;

    const int rows = Q + R;
    prep_kernel<<<(rows + 3) / 4, 256, 0, stream>>>(qe, re, qb, rb, qsq, rsq, counts, Q, R);

    dim3 grid(NSPLIT, Q / BM);   // (32, 32) = 1024 blocks = 4/CU
    dist_count_kernel<<<grid, 256, 0, stream>>>(qb, rb, qsq, rsq, thr, counts, Q, R);

    finalize_kernel<<<(Q + 255) / 256, 256, 0, stream>>>(counts, out, Q, R);
}